// Round 1
// baseline (148.329 us; speedup 1.0000x reference)
//
#include <hip/hip_runtime.h>
#include <hip/hip_bf16.h>
#include <stdint.h>

#define B_DIM   4096
#define IN_DIM  512
#define OUT_DIM 512
#define M_DIM   16
#define K_DIM   (IN_DIM * M_DIM)     // 8192
#define MN      (B_DIM * OUT_DIM)    // 2097152

typedef unsigned short ushort_t;
typedef __attribute__((ext_vector_type(8))) __bf16 bf16x8;
typedef __attribute__((ext_vector_type(4))) float  f32x4;

__device__ __forceinline__ ushort_t f2bf(float f) {
  union { float f; uint32_t u; } v; v.f = f;
  uint32_t u = v.u + 0x7fffu + ((v.u >> 16) & 1u);   // RNE
  return (ushort_t)(u >> 16);
}

// ---------- phase 1a: coeffs fp32 -> bf16 (layout [OUT][IN][M] == B^T [N][K]) ----------
__global__ __launch_bounds__(256) void convert_coeffs_kernel(
    const float* __restrict__ src, ushort_t* __restrict__ dst, int n4) {
  int i = blockIdx.x * 256 + threadIdx.x;
  if (i >= n4) return;
  float4 v = ((const float4*)src)[i];
  ushort4 o;
  o.x = f2bf(v.x); o.y = f2bf(v.y); o.z = f2bf(v.z); o.w = f2bf(v.w);
  ((ushort4*)dst)[i] = o;
}

// ---------- phase 1b: basis bf16 [B_DIM][IN_DIM*M_DIM], K index = i*16+m ----------
__global__ __launch_bounds__(256) void basis_kernel(
    const float* __restrict__ x, const float* __restrict__ bc,
    ushort_t* __restrict__ basis) {
  int idx = blockIdx.x * 256 + threadIdx.x;   // one (b,i) pair per thread
  float xv = x[idx];
  float x2 = xv * xv, x3 = x2 * xv, x4 = x2 * x2;
  const float LOG2E = 1.44269504088896340736f;
  const float LN2   = 0.69314718055994530942f;
  uint32_t w[8];
  #pragma unroll
  for (int m = 0; m < 16; ++m) {
    float b1 = bc[m*8+0], b2 = bc[m*8+1], b3 = bc[m*8+2], b4 = bc[m*8+3];
    float b5 = bc[m*8+4], b6 = bc[m*8+5], b7 = bc[m*8+6], b8 = bc[m*8+7];
    // inner = expm1(b3*x); powered = inner^b4; u = log1p(powered)
    float e     = __builtin_amdgcn_exp2f(b3 * xv * LOG2E);
    float inner = e - 1.0f;                                   // inner > 0 always (b3*x >= 0.01)
    float p     = __builtin_amdgcn_exp2f(b4 * __builtin_amdgcn_logf(inner));
    float u     = LN2 * __builtin_amdgcn_logf(1.0f + p);      // log1p(powered)
    float vv    = LN2 * __builtin_amdgcn_logf(1.0f + b2 * u); // log(1 + b2*u)
    float y = b1 * vv + b5 * xv + b6 * x2 + b7 * x3 + b8 * x4;
    uint32_t h = (uint32_t)f2bf(y);
    if (m & 1) w[m >> 1] |= (h << 16); else w[m >> 1] = h;
  }
  uint4* dst = (uint4*)(basis + (size_t)idx * 16);   // 32B contiguous per thread
  dst[0] = make_uint4(w[0], w[1], w[2], w[3]);
  dst[1] = make_uint4(w[4], w[5], w[6], w[7]);
}

// ---------- phase 2: GEMM C[M][N] = A[M][K] * Bt[N][K]^T, split-K ----------
#define BM 128
#define BN 128
#define BK 32
#define SPLITK 4
#define KC (K_DIM / SPLITK)   // 2048 per split -> 64 K-iterations

#define GLD16(g, l) \
  __builtin_amdgcn_global_load_lds((const __attribute__((address_space(1))) void*)(g), \
                                   (__attribute__((address_space(3))) void*)(l), 16, 0, 0)

template <int ATOMIC>
__global__ __launch_bounds__(256, 2) void gemm_kernel(
    const ushort_t* __restrict__ A,   // basis [B_DIM][K_DIM] bf16
    const ushort_t* __restrict__ Bt,  // coeffs [OUT_DIM][K_DIM] bf16
    float* __restrict__ P) {          // partials [SPLITK][B_DIM][OUT_DIM] or out [B][OUT]
  __shared__ __align__(16) ushort_t As[BM * BK];
  __shared__ __align__(16) ushort_t Bs[BN * BK];
  const int tid  = threadIdx.x;
  const int wave = tid >> 6;
  const int lane = tid & 63;
  const int bm = blockIdx.x, bn = blockIdx.y, ks = blockIdx.z;

  // staging: one global_load_lds(16B) covers 16 rows (4 lanes/row of 8 bf16)
  const int srow = wave * 16 + (lane >> 2);
  const int scol = (lane & 3) * 8;
  const ushort_t* Ag  = A  + (size_t)(bm * BM + srow) * K_DIM + (size_t)ks * KC + scol;
  const ushort_t* Bg  = Bt + (size_t)(bn * BN + srow) * K_DIM + (size_t)ks * KC + scol;
  const ushort_t* Ag2 = Ag + (size_t)64 * K_DIM;
  const ushort_t* Bg2 = Bg + (size_t)64 * K_DIM;
  ushort_t* AsW  = As + wave * 16 * BK;   // wave-uniform LDS base; HW adds lane*16B
  ushort_t* AsW2 = AsW + 64 * BK;
  ushort_t* BsW  = Bs + wave * 16 * BK;
  ushort_t* BsW2 = BsW + 64 * BK;

  // 2x2 wave grid; each wave computes 64x64 via 4x4 tiles of 16x16x32 MFMA
  const int wr = wave >> 1, wc = wave & 1;
  const int fm = lane & 15;          // A row / Bt row within 16-tile
  const int fk = (lane >> 4) * 8;    // k offset within BK

  f32x4 acc[4][4] = {};

  for (int kt = 0; kt < KC; kt += BK) {
    GLD16(Ag, AsW); GLD16(Ag2, AsW2);
    GLD16(Bg, BsW); GLD16(Bg2, BsW2);
    Ag += BK; Ag2 += BK; Bg += BK; Bg2 += BK;
    __syncthreads();   // drains vmcnt (global_load_lds) + lgkmcnt
    bf16x8 af[4], bfv[4];
    #pragma unroll
    for (int t = 0; t < 4; ++t) {
      af[t]  = *(const bf16x8*)(As + (wr * 64 + t * 16 + fm) * BK + fk);
      bfv[t] = *(const bf16x8*)(Bs + (wc * 64 + t * 16 + fm) * BK + fk);
    }
    #pragma unroll
    for (int mt = 0; mt < 4; ++mt)
      #pragma unroll
      for (int nt = 0; nt < 4; ++nt)
        acc[mt][nt] = __builtin_amdgcn_mfma_f32_16x16x32_bf16(af[mt], bfv[nt], acc[mt][nt], 0, 0, 0);
    __syncthreads();
  }

  // epilogue: C/D layout col = lane&15, row = (lane>>4)*4 + reg
  const int colb = bn * BN + wc * 64 + fm;
  const int rowb = bm * BM + wr * 64 + (lane >> 4) * 4;
  float* out = P + (ATOMIC ? (size_t)0 : (size_t)ks * MN);
  #pragma unroll
  for (int mt = 0; mt < 4; ++mt) {
    #pragma unroll
    for (int nt = 0; nt < 4; ++nt) {
      #pragma unroll
      for (int j = 0; j < 4; ++j) {
        int row = rowb + mt * 16 + j;
        int col = colb + nt * 16;
        float vv = acc[mt][nt][j];
        if (ATOMIC) atomicAdd(out + (size_t)row * OUT_DIM + col, vv);
        else        out[(size_t)row * OUT_DIM + col] = vv;
      }
    }
  }
}

// ---------- phase 3: reduce split-K partials ----------
__global__ __launch_bounds__(256) void reduce_kernel(
    const float* __restrict__ P, float* __restrict__ out) {
  int i = blockIdx.x * 256 + threadIdx.x;   // MN/4 threads
  const float4* p = (const float4*)P;
  float4 a = p[i], b = p[i + MN/4], c = p[i + 2*(MN/4)], d = p[i + 3*(MN/4)];
  float4 r = make_float4(a.x + b.x + c.x + d.x, a.y + b.y + c.y + d.y,
                         a.z + b.z + c.z + d.z, a.w + b.w + c.w + d.w);
  ((float4*)out)[i] = r;
}

extern "C" void kernel_launch(void* const* d_in, const int* in_sizes, int n_in,
                              void* d_out, int out_size, void* d_ws, size_t ws_size,
                              hipStream_t stream) {
  const float* x      = (const float*)d_in[0];   // [4096][512]
  const float* coeffs = (const float*)d_in[1];   // [512][512][16]
  const float* b_coef = (const float*)d_in[2];   // [16][8]
  float* out = (float*)d_out;
  char*  ws  = (char*)d_ws;

  const size_t BASIS_BYTES = (size_t)B_DIM * K_DIM * 2;     // 64 MiB
  const size_t COEF_BYTES  = (size_t)OUT_DIM * K_DIM * 2;   // 8 MiB
  ushort_t* basis = (ushort_t*)ws;
  ushort_t* coefb = (ushort_t*)(ws + BASIS_BYTES);
  float* partials = (float*)(ws + BASIS_BYTES + COEF_BYTES);
  const size_t FULL = BASIS_BYTES + COEF_BYTES + (size_t)SPLITK * MN * 4;
  const bool use_atomic = (ws_size < FULL);   // deterministic per-session branch

  convert_coeffs_kernel<<<(OUT_DIM * K_DIM / 4 + 255) / 256, 256, 0, stream>>>(
      coeffs, coefb, OUT_DIM * K_DIM / 4);
  basis_kernel<<<(B_DIM * IN_DIM) / 256, 256, 0, stream>>>(x, b_coef, basis);

  dim3 grid(B_DIM / BM, OUT_DIM / BN, SPLITK);   // 32 x 4 x 4 = 512 blocks
  if (use_atomic) {
    hipMemsetAsync(d_out, 0, (size_t)MN * 4, stream);
    gemm_kernel<1><<<grid, 256, 0, stream>>>(basis, coefb, out);
  } else {
    gemm_kernel<0><<<grid, 256, 0, stream>>>(basis, coefb, partials);
    reduce_kernel<<<MN / 4 / 256, 256, 0, stream>>>(partials, out);
  }
}